// Round 2
// 230.497 us; speedup vs baseline: 1.0210x; 1.0210x over previous
//
#include <hip/hip_runtime.h>
#include <hip/hip_fp16.h>

// GCN layer: h = x @ W_conv; conv = D^-1/2 (A+I) D^-1/2 h + b_conv; out = conv @ W_lin + b_lin
// N=50000, E=800000, in_c=256, hid=128.
// h, conv in bf16 row-major. CSR stored as packed u32 records (src u16 | fp16 weight).
//
// Pipeline (8 dispatches, stream-serial):
//   memset(deg) -> prep(W transposes + deg/rank grid-stride) -> scan_blocks
//   -> finalize2 (inlines the block-sum scan) -> bucket -> GEMM1 -> gather -> GEMM2
// GEMMs use BK=64 (LDK=72 pad; 144B row stride = 9 granules == 1 mod 8 -> conflict-free
// ds_read_b128/ds_write_b128), halving barrier drains vs BK=32.

#define N_NODES 50000
#define N_EDGES 800000
#define IN_C 256
#define HID 128
#define SCAN_BLOCKS ((N_NODES + 255) / 256)   // 196
#define GEMM_MBLK ((N_NODES + 63) / 64)       // 782
#define PREP_BLOCKS 1024
#define LDK 72                                 // 64 + 8 pad (bf16 elems)

// workspace layout (bytes)
#define OFF_H    0UL          // [N][128] bf16 = 12,800,000
#define OFF_CONV 12800000UL   // [N][128] bf16 = 12,800,000
#define OFF_DEG  25600000UL   // 50000 i32
#define OFF_RP   25800000UL   // 50001 i32 (pad to 64)
#define OFF_DINV 26000064UL   // 50000 f32
#define OFF_RANK 26200064UL   // 800000 u16 = 1,600,000
#define OFF_REC  27800064UL   // 800000 u32 = 3,200,000
#define OFF_BSUM 31000064UL   // 256 i32
#define OFF_WT1  31001088UL   // 128*256 bf16 (W_conv^T)
#define OFF_WT2  31066624UL   // 256*128 bf16 (W_lin^T)

typedef __attribute__((ext_vector_type(8))) short bf16x8;
typedef __attribute__((ext_vector_type(4))) float f32x4;

__device__ __forceinline__ ushort f2bf(float x) {
    unsigned u = __float_as_uint(x);
    u += 0x7fffu + ((u >> 16) & 1u);       // round-to-nearest-even
    return (ushort)(u >> 16);
}

// fused: transpose both weight matrices to bf16 [N][K] + deg count / rank capture.
// deg must be zeroed before this kernel (memset on the same stream).
__global__ __launch_bounds__(256) void prep_kernel(
    const float* __restrict__ Wc, const float* __restrict__ Wl,
    ushort* __restrict__ wtc, ushort* __restrict__ wtl,
    const int* __restrict__ dst, ushort* __restrict__ rank, int* __restrict__ deg)
{
    int i = blockIdx.x * 256 + threadIdx.x;
    if (i < HID * IN_C) {                            // W_conv [256][128] -> [128][256]
        int n = i / IN_C, k = i % IN_C;
        wtc[i] = f2bf(Wc[k * HID + n]);
    } else if (i < 2 * HID * IN_C) {                 // W_lin [128][256] -> [256][128]
        int j = i - HID * IN_C;
        int n = j / HID, k = j % HID;
        wtl[j] = f2bf(Wl[k * IN_C + n]);
    }
    for (int e = i; e < N_EDGES; e += PREP_BLOCKS * 256)
        rank[e] = (ushort)atomicAdd(&deg[dst[e]], 1);
}

__global__ __launch_bounds__(256) void scan_blocks_kernel(
    const int* __restrict__ deg, int* __restrict__ row_ptr,
    int* __restrict__ bsums, int n)
{
    __shared__ int tmp[256];
    int tid = threadIdx.x;
    int i = blockIdx.x * 256 + tid;
    int v = (i < n) ? deg[i] : 0;
    int orig = v;
    tmp[tid] = v;
    __syncthreads();
    #pragma unroll
    for (int off = 1; off < 256; off <<= 1) {
        int t = (tid >= off) ? tmp[tid - off] : 0;
        __syncthreads();
        tmp[tid] += t;
        __syncthreads();
    }
    if (i < n) row_ptr[i] = tmp[tid] - orig;
    if (tid == 255) bsums[blockIdx.x] = tmp[255];
}

// finalize with inlined block-sum scan: every block redundantly scans bsums[0..195]
// in LDS (cheap), then applies its own exclusive offset. Removes the scan_sums launch.
__global__ __launch_bounds__(256) void finalize2_kernel(
    const int* __restrict__ deg, int* __restrict__ row_ptr,
    const int* __restrict__ bsums, float* __restrict__ dinv, int n)
{
    __shared__ int tmp[256];
    __shared__ int orig[256];
    int tid = threadIdx.x;
    int v = (tid < SCAN_BLOCKS) ? bsums[tid] : 0;
    tmp[tid] = v;
    orig[tid] = v;
    __syncthreads();
    #pragma unroll
    for (int off = 1; off < 256; off <<= 1) {
        int t = (tid >= off) ? tmp[tid - off] : 0;
        __syncthreads();
        tmp[tid] += t;
        __syncthreads();
    }
    int boff = tmp[blockIdx.x] - orig[blockIdx.x];   // exclusive prefix for this block
    int i = blockIdx.x * 256 + tid;
    if (i < n) {
        row_ptr[i] += boff;
        dinv[i] = rsqrtf((float)(deg[i] + 1));
    }
    if (i == 0) row_ptr[n] = N_EDGES;
}

// CSR fill, atomic-free, XCD-class filtered (blockIdx%8 handles one dst range).
// rec = src u16 | fp16(dinv[src]) << 16.
#define BUCKET_BLOCKS 2048
__global__ __launch_bounds__(256) void bucket_kernel(
    const int* __restrict__ src, const int* __restrict__ dst,
    const ushort* __restrict__ rank, const int* __restrict__ row_ptr,
    const float* __restrict__ dinv, unsigned* __restrict__ rec)
{
    int cls = blockIdx.x & 7;
    int blk = blockIdx.x >> 3;                 // 0..255
    int lo = cls * (N_NODES / 8);              // 6250 per class
    int hi = lo + (N_NODES / 8);
    const int CHUNK = (N_EDGES + 255) / 256;   // 3125
    int e0 = blk * CHUNK;
    int e1 = min(e0 + CHUNK, N_EDGES);
    for (int i = e0 + threadIdx.x; i < e1; i += 256) {
        int d = dst[i];
        if (d >= lo && d < hi) {
            int s = src[i];
            unsigned r = (unsigned)(ushort)s |
                         ((unsigned)__half_as_ushort(__float2half_rn(dinv[s])) << 16);
            rec[row_ptr[d] + rank[i]] = r;
        }
    }
}

// C[M,N] = A[M,K] @ B[K,N] (+bias) via bf16 MFMA 16x16x32. Tile 64x128, BK=64.
// Two K-chunks of 32 per barrier pair -> 16 MFMA per sync, half the waitcnt drains.
template <bool A_IS_BF16, bool BF16OUT>
__global__ __launch_bounds__(256) void mfma_gemm_kernel(
    const void* __restrict__ Av, const ushort* __restrict__ Bt,
    const float* __restrict__ bias, void* __restrict__ Cv,
    int M, int N, int K)
{
    __shared__ __align__(16) ushort As[64 * LDK];
    __shared__ __align__(16) ushort Bs[128 * LDK];
    int tid = threadIdx.x;
    int wave = tid >> 6, lane = tid & 63;
    int quad = lane >> 4, l16 = lane & 15;
    int wm0 = (wave >> 1) * 32, wn0 = (wave & 1) * 64;
    int bm = blockIdx.x * 64, bn = blockIdx.y * 128;

    f32x4 acc[2][4] = {};

    for (int k0 = 0; k0 < K; k0 += 64) {
        {   // A stage: 64 rows x 64 k, 16 elems/thread
            int row = tid >> 2, col = (tid & 3) * 16;
            int grow = bm + row;
            if (A_IS_BF16) {
                bf16x8 v0 = {}, v1 = {};
                if (grow < M) {
                    const ushort* ap = (const ushort*)Av + (size_t)grow * K + k0 + col;
                    v0 = *(const bf16x8*)ap;
                    v1 = *(const bf16x8*)(ap + 8);
                }
                *(bf16x8*)&As[row * LDK + col]     = v0;
                *(bf16x8*)&As[row * LDK + col + 8] = v1;
            } else {
                float4 v0 = {}, v1 = {}, v2 = {}, v3 = {};
                if (grow < M) {
                    const float* ap = (const float*)Av + (size_t)grow * K + k0 + col;
                    v0 = *(const float4*)ap;
                    v1 = *(const float4*)(ap + 4);
                    v2 = *(const float4*)(ap + 8);
                    v3 = *(const float4*)(ap + 12);
                }
                ushort t0[8] = {f2bf(v0.x), f2bf(v0.y), f2bf(v0.z), f2bf(v0.w),
                                f2bf(v1.x), f2bf(v1.y), f2bf(v1.z), f2bf(v1.w)};
                ushort t1[8] = {f2bf(v2.x), f2bf(v2.y), f2bf(v2.z), f2bf(v2.w),
                                f2bf(v3.x), f2bf(v3.y), f2bf(v3.z), f2bf(v3.w)};
                *(bf16x8*)&As[row * LDK + col]     = *(bf16x8*)t0;
                *(bf16x8*)&As[row * LDK + col + 8] = *(bf16x8*)t1;
            }
        }
        {   // B stage: 128 rows x 64 k, 32 elems/thread
            int n = tid >> 1;
            int kk = (tid & 1) * 32;
            const ushort* bp = Bt + (size_t)(bn + n) * K + k0 + kk;
            *(bf16x8*)&Bs[n * LDK + kk]      = *(const bf16x8*)bp;
            *(bf16x8*)&Bs[n * LDK + kk + 8]  = *(const bf16x8*)(bp + 8);
            *(bf16x8*)&Bs[n * LDK + kk + 16] = *(const bf16x8*)(bp + 16);
            *(bf16x8*)&Bs[n * LDK + kk + 24] = *(const bf16x8*)(bp + 24);
        }
        __syncthreads();
        bf16x8 af[2][2], bfr[4][2];
        #pragma unroll
        for (int im = 0; im < 2; ++im)
            #pragma unroll
            for (int kh = 0; kh < 2; ++kh)
                af[im][kh] = *(bf16x8*)&As[(wm0 + im * 16 + l16) * LDK + kh * 32 + quad * 8];
        #pragma unroll
        for (int in = 0; in < 4; ++in)
            #pragma unroll
            for (int kh = 0; kh < 2; ++kh)
                bfr[in][kh] = *(bf16x8*)&Bs[(wn0 + in * 16 + l16) * LDK + kh * 32 + quad * 8];
        #pragma unroll
        for (int im = 0; im < 2; ++im)
            #pragma unroll
            for (int in = 0; in < 4; ++in) {
                acc[im][in] = __builtin_amdgcn_mfma_f32_16x16x32_bf16(
                    af[im][0], bfr[in][0], acc[im][in], 0, 0, 0);
                acc[im][in] = __builtin_amdgcn_mfma_f32_16x16x32_bf16(
                    af[im][1], bfr[in][1], acc[im][in], 0, 0, 0);
            }
        __syncthreads();
    }
    #pragma unroll
    for (int im = 0; im < 2; ++im) {
        #pragma unroll
        for (int in = 0; in < 4; ++in) {
            int col = bn + wn0 + in * 16 + l16;
            float bval = bias ? bias[col] : 0.f;
            #pragma unroll
            for (int r = 0; r < 4; ++r) {
                int grow = bm + wm0 + im * 16 + quad * 4 + r;
                if (grow < M) {
                    float o = acc[im][in][r] + bval;
                    if (BF16OUT)
                        ((ushort*)Cv)[(size_t)grow * N + col] = f2bf(o);
                    else
                        ((float*)Cv)[(size_t)grow * N + col] = o;
                }
            }
        }
    }
}

// ---------------- gather ----------------
// convb[d][:] = bf16( di*( sum_in w_s*h[s][:] + di*h[d][:] ) + b_conv )
// wave64 per node; two 32-lane halves process alternate edges, unroll 4 per half.
__device__ __forceinline__ void acc_edge(float4& acc, unsigned r,
                                         const ushort* __restrict__ hb, int c) {
    unsigned s = r & 0xffffu;
    float w = __half2float(__ushort_as_half((ushort)(r >> 16)));
    uint2 v = *(const uint2*)&hb[(size_t)s * HID + c];
    acc.x += w * __uint_as_float(v.x << 16);
    acc.y += w * __uint_as_float(v.x & 0xffff0000u);
    acc.z += w * __uint_as_float(v.y << 16);
    acc.w += w * __uint_as_float(v.y & 0xffff0000u);
}

__global__ __launch_bounds__(256) void gather_kernel(
    const ushort* __restrict__ hb, const int* __restrict__ row_ptr,
    const unsigned* __restrict__ rec, const float* __restrict__ dinv,
    const float* __restrict__ b_conv, ushort* __restrict__ convb, int n)
{
    int wave = threadIdx.x >> 6;
    int lane = threadIdx.x & 63;
    int d = blockIdx.x * 4 + wave;
    if (d >= n) return;
    int half = lane >> 5;
    int l32 = lane & 31;
    int c = l32 << 2;                 // 4 cols per lane

    float4 acc = make_float4(0.f, 0.f, 0.f, 0.f);
    int begin = row_ptr[d], end = row_ptr[d + 1];
    int e = begin + half;             // this half's edges: e, e+2, e+4, ...
    for (; e + 6 < end; e += 8) {
        unsigned r0 = rec[e];
        unsigned r1 = rec[e + 2];
        unsigned r2 = rec[e + 4];
        unsigned r3 = rec[e + 6];
        acc_edge(acc, r0, hb, c);
        acc_edge(acc, r1, hb, c);
        acc_edge(acc, r2, hb, c);
        acc_edge(acc, r3, hb, c);
    }
    for (; e < end; e += 2) {
        unsigned r0 = rec[e];
        acc_edge(acc, r0, hb, c);
    }
    acc.x += __shfl_xor(acc.x, 32);
    acc.y += __shfl_xor(acc.y, 32);
    acc.z += __shfl_xor(acc.z, 32);
    acc.w += __shfl_xor(acc.w, 32);

    if (half == 0) {
        float di = dinv[d];
        uint2 hv = *(const uint2*)&hb[(size_t)d * HID + c];
        acc.x += di * __uint_as_float(hv.x << 16);
        acc.y += di * __uint_as_float(hv.x & 0xffff0000u);
        acc.z += di * __uint_as_float(hv.y << 16);
        acc.w += di * __uint_as_float(hv.y & 0xffff0000u);
        float4 bb = *(const float4*)&b_conv[c];
        float ox = di * acc.x + bb.x;
        float oy = di * acc.y + bb.y;
        float oz = di * acc.z + bb.z;
        float ow = di * acc.w + bb.w;
        uint2 po;
        po.x = ((unsigned)f2bf(oy) << 16) | (unsigned)f2bf(ox);
        po.y = ((unsigned)f2bf(ow) << 16) | (unsigned)f2bf(oz);
        *(uint2*)&convb[(size_t)d * HID + c] = po;
    }
}

extern "C" void kernel_launch(void* const* d_in, const int* in_sizes, int n_in,
                              void* d_out, int out_size, void* d_ws, size_t ws_size,
                              hipStream_t stream) {
    const float* x      = (const float*)d_in[0];
    const int*   ei     = (const int*)d_in[1];
    const float* W_conv = (const float*)d_in[2];
    const float* b_conv = (const float*)d_in[3];
    const float* W_lin  = (const float*)d_in[4];
    const float* b_lin  = (const float*)d_in[5];
    float* out = (float*)d_out;

    char* ws = (char*)d_ws;
    ushort* hb      = (ushort*)(ws + OFF_H);
    ushort* convb   = (ushort*)(ws + OFF_CONV);
    int*    deg     = (int*)(ws + OFF_DEG);
    int*    row_ptr = (int*)(ws + OFF_RP);
    float*  dinv    = (float*)(ws + OFF_DINV);
    ushort* rank    = (ushort*)(ws + OFF_RANK);
    unsigned* rec   = (unsigned*)(ws + OFF_REC);
    int*    bsums   = (int*)(ws + OFF_BSUM);
    ushort* wt_conv = (ushort*)(ws + OFF_WT1);
    ushort* wt_lin  = (ushort*)(ws + OFF_WT2);

    const int* src = ei;
    const int* dst = ei + N_EDGES;

    hipMemsetAsync(deg, 0, 200000, stream);

    // K1: W transposes + deg/rank (fuses 3 old dispatches)
    prep_kernel<<<PREP_BLOCKS, 256, 0, stream>>>(W_conv, W_lin, wt_conv, wt_lin,
                                                 dst, rank, deg);
    // K2-K3: CSR build
    scan_blocks_kernel<<<SCAN_BLOCKS, 256, 0, stream>>>(deg, row_ptr, bsums, N_NODES);
    finalize2_kernel<<<SCAN_BLOCKS, 256, 0, stream>>>(deg, row_ptr, bsums, dinv, N_NODES);
    bucket_kernel<<<BUCKET_BLOCKS, 256, 0, stream>>>(src, dst, rank, row_ptr, dinv, rec);

    // K4: h = bf16(x @ W_conv)
    mfma_gemm_kernel<false, true><<<dim3(GEMM_MBLK, HID / 128), 256, 0, stream>>>(
        x, wt_conv, nullptr, hb, N_NODES, HID, IN_C);

    // K5: gather
    gather_kernel<<<(N_NODES + 3) / 4, 256, 0, stream>>>(
        hb, row_ptr, rec, dinv, b_conv, convb, N_NODES);

    // K6: out = conv @ W_lin + b_lin
    mfma_gemm_kernel<true, false><<<dim3(GEMM_MBLK, IN_C / 128), 256, 0, stream>>>(
        convb, wt_lin, b_lin, out, N_NODES, IN_C, HID);
}